// Round 1
// baseline (38800.299 us; speedup 1.0000x reference)
//
#include <hip/hip_runtime.h>
#include <cstddef>
#include <cstdint>

#define B 32
#define TENC 2048
#define DD 512
#define TDEC 128
#define UU 512
#define NCH 16
#define TCHUNK 128

// ---------------- xW1 = enc @ W1 : [65536,512] x [512,512] fp32 ----------------
__global__ void gemm_xw1_kernel(const float* __restrict__ A, const float* __restrict__ Bm,
                                float* __restrict__ C) {
    __shared__ float As[16][65];
    __shared__ float Bs[16][65];
    int bm = blockIdx.y * 64, bn = blockIdx.x * 64;
    int tx = threadIdx.x & 15, ty = threadIdx.x >> 4;
    float acc[4][4] = {};
    for (int k0 = 0; k0 < 512; k0 += 16) {
#pragma unroll
        for (int i = 0; i < 4; i++) {
            int idx = threadIdx.x + 256 * i;
            int r = idx >> 4, kk = idx & 15;
            As[kk][r] = A[(size_t)(bm + r) * 512 + k0 + kk];
            int cc = idx & 63, kb = idx >> 6;
            Bs[kb][cc] = Bm[(size_t)(k0 + kb) * 512 + bn + cc];
        }
        __syncthreads();
#pragma unroll
        for (int kk = 0; kk < 16; kk++) {
            float a[4], b[4];
#pragma unroll
            for (int i = 0; i < 4; i++) a[i] = As[kk][ty * 4 + i];
#pragma unroll
            for (int j = 0; j < 4; j++) b[j] = Bs[kk][tx * 4 + j];
#pragma unroll
            for (int i = 0; i < 4; i++)
#pragma unroll
                for (int j = 0; j < 4; j++) acc[i][j] += a[i] * b[j];
        }
        __syncthreads();
    }
#pragma unroll
    for (int i = 0; i < 4; i++)
#pragma unroll
        for (int j = 0; j < 4; j++)
            C[(size_t)(bm + ty * 4 + i) * 512 + bn + tx * 4 + j] = acc[i][j];
}

// ---------------- hW2 = h @ W2 + b2 : [32,512] ----------------
__global__ void hw2_kernel(const float* __restrict__ h, const float* __restrict__ W2,
                           const float* __restrict__ b2, float* __restrict__ hW2) {
    int b = blockIdx.x;
    int d = blockIdx.y * 256 + threadIdx.x;
    __shared__ float hs[512];
    hs[threadIdx.x] = h[b * 512 + threadIdx.x];
    hs[threadIdx.x + 256] = h[b * 512 + threadIdx.x + 256];
    __syncthreads();
    float acc = b2[d];
#pragma unroll 8
    for (int u = 0; u < 512; u++) acc += hs[u] * W2[(size_t)u * 512 + d];
    hW2[b * 512 + d] = acc;
}

// ---- fused score + partial-softmax + partial-context over a T_enc chunk ----
// grid (32, 16); block 256. Each block: 128 t positions of batch b.
__global__ void attn_kernel(const float* __restrict__ xW1, const float* __restrict__ enc,
                            const float* __restrict__ hW2, const float* __restrict__ Vv,
                            float* __restrict__ pm, float* __restrict__ pl,
                            float* __restrict__ pacc) {
    int b = blockIdx.x, ch = blockIdx.y;
    int t0 = ch * TCHUNK;
    int tid = threadIdx.x;
    __shared__ float hs[512], Vs[512], sc[TCHUNK], red[8];
    hs[tid] = hW2[b * 512 + tid];
    hs[tid + 256] = hW2[b * 512 + tid + 256];
    Vs[tid] = Vv[tid];
    Vs[tid + 256] = Vv[tid + 256];
    __syncthreads();
    int wave = tid >> 6, lane = tid & 63;
    // scores: one wave handles 32 consecutive t, lanes split d
    for (int tt = wave * 32; tt < wave * 32 + 32; ++tt) {
        const float* row = xW1 + ((size_t)b * TENC + t0 + tt) * 512;
        float s = 0.f;
#pragma unroll
        for (int i = 0; i < 8; i++) {
            int d = lane + i * 64;
            s += tanhf(row[d] + hs[d]) * Vs[d];
        }
#pragma unroll
        for (int off = 32; off >= 1; off >>= 1) s += __shfl_down(s, off, 64);
        if (lane == 0) sc[tt] = s;
    }
    __syncthreads();
    // block max
    float lm = (tid < TCHUNK) ? sc[tid] : -1e30f;
#pragma unroll
    for (int off = 32; off >= 1; off >>= 1) lm = fmaxf(lm, __shfl_down(lm, off, 64));
    if (lane == 0) red[wave] = lm;
    __syncthreads();
    float m = fmaxf(fmaxf(red[0], red[1]), fmaxf(red[2], red[3]));
    __syncthreads();
    // p = exp(s - m), l = sum p
    float lp = 0.f;
    if (tid < TCHUNK) {
        float p = expf(sc[tid] - m);
        sc[tid] = p;
        lp = p;
    }
#pragma unroll
    for (int off = 32; off >= 1; off >>= 1) lp += __shfl_down(lp, off, 64);
    if (lane == 0) red[4 + wave] = lp;
    __syncthreads();
    float l = red[4] + red[5] + red[6] + red[7];
    // partial context: acc[d] = sum_t p[t]*enc[b,t,d]; thread owns d=tid, d=tid+256
    float a0 = 0.f, a1 = 0.f;
#pragma unroll 4
    for (int t = 0; t < TCHUNK; t++) {
        float p = sc[t];
        const float* e = enc + ((size_t)b * TENC + t0 + t) * 512;
        a0 += p * e[tid];
        a1 += p * e[tid + 256];
    }
    size_t po = ((size_t)(b * NCH + ch)) * 512;
    pacc[po + tid] = a0;
    pacc[po + tid + 256] = a1;
    if (tid == 0) {
        pm[b * NCH + ch] = m;
        pl[b * NCH + ch] = l;
    }
}

// ---------------- combine chunk partials -> Xa[b,d] ----------------
__global__ void combine_kernel(const float* __restrict__ pm, const float* __restrict__ pl,
                               const float* __restrict__ pacc, float* __restrict__ Xa) {
    int b = blockIdx.x, tid = threadIdx.x;
    __shared__ float w[NCH];
    float mg = -1e30f;
#pragma unroll
    for (int i = 0; i < NCH; i++) mg = fmaxf(mg, pm[b * NCH + i]);
    float L = 0.f;
#pragma unroll
    for (int i = 0; i < NCH; i++) L += pl[b * NCH + i] * expf(pm[b * NCH + i] - mg);
    if (tid < NCH) w[tid] = expf(pm[b * NCH + tid] - mg);
    __syncthreads();
    float inv = 1.f / L;
    for (int d = tid; d < 512; d += 256) {
        float s = 0.f;
#pragma unroll
        for (int i = 0; i < NCH; i++) s += w[i] * pacc[((size_t)(b * NCH + i)) * 512 + d];
        Xa[b * 512 + d] = s * inv;
    }
}

// ---------------- h_in = concat(x_t, Xa) @ W3 + b3 ----------------
__global__ void mix_kernel(const float* __restrict__ dec, const float* __restrict__ Xa,
                           const float* __restrict__ W3, const float* __restrict__ b3,
                           float* __restrict__ h_in, int t) {
    int b = blockIdx.x;
    int u = blockIdx.y * 256 + threadIdx.x;
    __shared__ float s[1024];
    const float* xt = dec + ((size_t)b * TDEC + t) * 512;
    s[threadIdx.x] = xt[threadIdx.x];
    s[threadIdx.x + 256] = xt[threadIdx.x + 256];
    s[threadIdx.x + 512] = Xa[b * 512 + threadIdx.x];
    s[threadIdx.x + 768] = Xa[b * 512 + threadIdx.x + 256];
    __syncthreads();
    float acc = b3[u];
#pragma unroll 8
    for (int k = 0; k < 1024; k++) acc += s[k] * W3[(size_t)k * 512 + u];
    h_in[b * 512 + u] = acc;
}

// ---------------- z = h_in @ Wk + h @ Wr + bias : [32, 2048] ----------------
// grid 128 (g-chunks of 16), block 256: tx=g (16), ty=b-slot (16) -> b=ty, ty+16
__global__ void z_kernel(const float* __restrict__ h_in, const float* __restrict__ h,
                         const float* __restrict__ Wk, const float* __restrict__ Wr,
                         const float* __restrict__ bias, float* __restrict__ z) {
    int gc = blockIdx.x * 16;
    int tx = threadIdx.x & 15, ty = threadIdx.x >> 4;
    __shared__ float his[32][65], hcs[32][65], Ks[64][16], Rs[64][16];
    float acc0 = 0.f, acc1 = 0.f;
    for (int u0 = 0; u0 < 512; u0 += 64) {
#pragma unroll
        for (int i = 0; i < 8; i++) {
            int idx = threadIdx.x + 256 * i;
            int bb = idx >> 6, uu = idx & 63;
            his[bb][uu] = h_in[bb * 512 + u0 + uu];
            hcs[bb][uu] = h[bb * 512 + u0 + uu];
        }
#pragma unroll
        for (int i = 0; i < 4; i++) {
            int idx = threadIdx.x + 256 * i;
            int uu = idx >> 4, gg = idx & 15;
            Ks[uu][gg] = Wk[(size_t)(u0 + uu) * 2048 + gc + gg];
            Rs[uu][gg] = Wr[(size_t)(u0 + uu) * 2048 + gc + gg];
        }
        __syncthreads();
#pragma unroll
        for (int u = 0; u < 64; u++) {
            float kv = Ks[u][tx], rv = Rs[u][tx];
            acc0 += his[ty][u] * kv + hcs[ty][u] * rv;
            acc1 += his[ty + 16][u] * kv + hcs[ty + 16][u] * rv;
        }
        __syncthreads();
    }
    float bv = bias[gc + tx];
    z[(size_t)ty * 2048 + gc + tx] = acc0 + bv;
    z[(size_t)(ty + 16) * 2048 + gc + tx] = acc1 + bv;
}

// ---------------- gates + state update + output write ----------------
__global__ void gate_kernel(const float* __restrict__ z, float* __restrict__ c,
                            float* __restrict__ h, float* __restrict__ out, int t) {
    int idx = blockIdx.x * 256 + threadIdx.x;  // 0..16383
    int b = idx >> 9, u = idx & 511;
    const float* zb = z + (size_t)b * 2048;
    float zi = zb[u], zf = zb[512 + u], zg = zb[1024 + u], zo = zb[1536 + u];
    float ig = 1.f / (1.f + expf(-zi));
    float fg = 1.f / (1.f + expf(-zf));
    float gg = tanhf(zg);
    float og = 1.f / (1.f + expf(-zo));
    float cn = fg * c[idx] + ig * gg;
    float hn = og * tanhf(cn);
    c[idx] = cn;
    h[idx] = hn;
    out[((size_t)b * TDEC + t) * 512 + u] = hn;
}

extern "C" void kernel_launch(void* const* d_in, const int* in_sizes, int n_in,
                              void* d_out, int out_size, void* d_ws, size_t ws_size,
                              hipStream_t stream) {
    const float* enc = (const float*)d_in[0];
    const float* dec = (const float*)d_in[1];
    const float* W1 = (const float*)d_in[2];
    const float* W2 = (const float*)d_in[3];
    const float* b2 = (const float*)d_in[4];
    const float* V = (const float*)d_in[5];
    const float* W3 = (const float*)d_in[6];
    const float* b3 = (const float*)d_in[7];
    const float* Wk = (const float*)d_in[8];
    const float* Wr = (const float*)d_in[9];
    const float* bias = (const float*)d_in[10];
    float* out = (float*)d_out;

    float* ws = (float*)d_ws;
    size_t o = 0;
    float* xW1 = ws + o;  o += (size_t)B * TENC * 512;   // 33,554,432
    float* h = ws + o;    o += B * 512;
    float* c = ws + o;    o += B * 512;
    float* hW2 = ws + o;  o += B * 512;
    float* pm = ws + o;   o += B * NCH;
    float* pl = ws + o;   o += B * NCH;
    float* pacc = ws + o; o += (size_t)B * NCH * 512;
    float* Xa = ws + o;   o += B * 512;
    float* h_in = ws + o; o += B * 512;
    float* z = ws + o;    o += B * 2048;

    // h, c are contiguous: zero both (ws is poisoned 0xAA before every call)
    hipMemsetAsync(h, 0, (size_t)2 * B * 512 * sizeof(float), stream);

    gemm_xw1_kernel<<<dim3(8, 1024), 256, 0, stream>>>(enc, W1, xW1);

    for (int t = 0; t < TDEC; t++) {
        hw2_kernel<<<dim3(32, 2), 256, 0, stream>>>(h, W2, b2, hW2);
        attn_kernel<<<dim3(32, NCH), 256, 0, stream>>>(xW1, enc, hW2, V, pm, pl, pacc);
        combine_kernel<<<32, 256, 0, stream>>>(pm, pl, pacc, Xa);
        mix_kernel<<<dim3(32, 2), 256, 0, stream>>>(dec, Xa, W3, b3, h_in, t);
        z_kernel<<<128, 256, 0, stream>>>(h_in, h, Wk, Wr, bias, z);
        gate_kernel<<<64, 256, 0, stream>>>(z, c, h, out, t);
    }
}

// Round 2
// 21102.789 us; speedup vs baseline: 1.8386x; 1.8386x over previous
//
#include <hip/hip_runtime.h>
#include <cstddef>
#include <cstdint>

#define B 32
#define TENC 2048
#define DD 512
#define TDEC 128
#define UU 512
#define NCH 16
#define TCH 128  // t positions per attn block (4 waves x 32)

typedef unsigned short ushort_t;

// ---------------- helpers ----------------
__device__ __forceinline__ uint16_t f2bf(float x) {
    uint32_t u = __float_as_uint(x);
    u += 0x7fffu + ((u >> 16) & 1u);  // RNE
    return (uint16_t)(u >> 16);
}
__device__ __forceinline__ void unpack8(uint4 v, float* f) {
    f[0] = __uint_as_float(v.x << 16); f[1] = __uint_as_float(v.x & 0xffff0000u);
    f[2] = __uint_as_float(v.y << 16); f[3] = __uint_as_float(v.y & 0xffff0000u);
    f[4] = __uint_as_float(v.z << 16); f[5] = __uint_as_float(v.z & 0xffff0000u);
    f[6] = __uint_as_float(v.w << 16); f[7] = __uint_as_float(v.w & 0xffff0000u);
}
__device__ __forceinline__ float fast_tanh(float x) {
    float e = __expf(2.f * x);                      // v_exp path; inf/0 give +-1 exactly
    return 1.f - 2.f * __builtin_amdgcn_rcpf(e + 1.f);
}
__device__ __forceinline__ float fast_sig(float x) {
    return __builtin_amdgcn_rcpf(1.f + __expf(-x));
}

// ---------------- one-time: enc fp32 -> bf16 ----------------
__global__ void cvt_kernel(const float* __restrict__ in, ushort_t* __restrict__ out) {
    int i = blockIdx.x * 256 + threadIdx.x;  // each handles 8 elements
    const float4* ip = (const float4*)in;
    float4 a = ip[2 * i], b = ip[2 * i + 1];
    uint4 o;
    o.x = (uint32_t)f2bf(a.x) | ((uint32_t)f2bf(a.y) << 16);
    o.y = (uint32_t)f2bf(a.z) | ((uint32_t)f2bf(a.w) << 16);
    o.z = (uint32_t)f2bf(b.x) | ((uint32_t)f2bf(b.y) << 16);
    o.w = (uint32_t)f2bf(b.z) | ((uint32_t)f2bf(b.w) << 16);
    ((uint4*)out)[i] = o;
}

// -------- one-time: xW1 = enc @ W1 (fp32 math, bf16 out) --------
__global__ void gemm_xw1_kernel(const float* __restrict__ A, const float* __restrict__ Bm,
                                ushort_t* __restrict__ C) {
    __shared__ float As[16][65];
    __shared__ float Bs[16][65];
    int bm = blockIdx.y * 64, bn = blockIdx.x * 64;
    int tx = threadIdx.x & 15, ty = threadIdx.x >> 4;
    float acc[4][4] = {};
    for (int k0 = 0; k0 < 512; k0 += 16) {
#pragma unroll
        for (int i = 0; i < 4; i++) {
            int idx = threadIdx.x + 256 * i;
            int r = idx >> 4, kk = idx & 15;
            As[kk][r] = A[(size_t)(bm + r) * 512 + k0 + kk];
            int cc = idx & 63, kb = idx >> 6;
            Bs[kb][cc] = Bm[(size_t)(k0 + kb) * 512 + bn + cc];
        }
        __syncthreads();
#pragma unroll
        for (int kk = 0; kk < 16; kk++) {
            float a[4], b[4];
#pragma unroll
            for (int i = 0; i < 4; i++) a[i] = As[kk][ty * 4 + i];
#pragma unroll
            for (int j = 0; j < 4; j++) b[j] = Bs[kk][tx * 4 + j];
#pragma unroll
            for (int i = 0; i < 4; i++)
#pragma unroll
                for (int j = 0; j < 4; j++) acc[i][j] += a[i] * b[j];
        }
        __syncthreads();
    }
#pragma unroll
    for (int i = 0; i < 4; i++) {
        uint2 o;
        o.x = (uint32_t)f2bf(acc[i][0]) | ((uint32_t)f2bf(acc[i][1]) << 16);
        o.y = (uint32_t)f2bf(acc[i][2]) | ((uint32_t)f2bf(acc[i][3]) << 16);
        *(uint2*)(C + (size_t)(bm + ty * 4 + i) * 512 + bn + tx * 4) = o;
    }
}

// ---------------- hW2 = h @ W2 + b2 : [32,512] ----------------
__global__ void hw2_kernel(const float* __restrict__ h, const float* __restrict__ W2,
                           const float* __restrict__ b2, float* __restrict__ hW2) {
    int b = blockIdx.x;
    int d = blockIdx.y * 256 + threadIdx.x;
    __shared__ float hs[512];
    hs[threadIdx.x] = h[b * 512 + threadIdx.x];
    hs[threadIdx.x + 256] = h[b * 512 + threadIdx.x + 256];
    __syncthreads();
    float acc = b2[d];
#pragma unroll 8
    for (int u = 0; u < 512; u++) acc += hs[u] * W2[(size_t)u * 512 + d];
    hW2[b * 512 + d] = acc;
}

// ---- single-pass online-softmax attention over a T_enc chunk (bf16 data) ----
// grid (32, NCH); block 256 = 4 waves; wave handles 32 consecutive t.
// Lane owns d = lane*8 .. lane*8+7 (hW2 row + V in registers).
__global__ void attn_kernel(const ushort_t* __restrict__ xW1h, const ushort_t* __restrict__ ench,
                            const float* __restrict__ hW2, const float* __restrict__ Vv,
                            float* __restrict__ pm, float* __restrict__ pl,
                            float* __restrict__ pacc) {
    int b = blockIdx.x, ch = blockIdx.y;
    int tid = threadIdx.x, wave = tid >> 6, lane = tid & 63;

    float hs[8], vs[8];
    {
        const float4* hp = (const float4*)(hW2 + b * 512 + lane * 8);
        float4 h0 = hp[0], h1 = hp[1];
        hs[0] = h0.x; hs[1] = h0.y; hs[2] = h0.z; hs[3] = h0.w;
        hs[4] = h1.x; hs[5] = h1.y; hs[6] = h1.z; hs[7] = h1.w;
        const float4* vp = (const float4*)(Vv + lane * 8);
        float4 v0 = vp[0], v1 = vp[1];
        vs[0] = v0.x; vs[1] = v0.y; vs[2] = v0.z; vs[3] = v0.w;
        vs[4] = v1.x; vs[5] = v1.y; vs[6] = v1.z; vs[7] = v1.w;
    }

    int t0 = ch * TCH + wave * 32;
    const uint4* xr = (const uint4*)xW1h + ((size_t)b * TENC + t0) * 64 + lane;
    const uint4* er = (const uint4*)ench + ((size_t)b * TENC + t0) * 64 + lane;

    float m = -INFINITY, l = 0.f;
    float acc[8] = {0.f, 0.f, 0.f, 0.f, 0.f, 0.f, 0.f, 0.f};

#pragma unroll 2
    for (int tt = 0; tt < 32; ++tt) {
        uint4 xv = xr[tt * 64];
        uint4 ev = er[tt * 64];
        float xf[8], ef[8];
        unpack8(xv, xf);
        float s = 0.f;
#pragma unroll
        for (int j = 0; j < 8; j++) s += fast_tanh(xf[j] + hs[j]) * vs[j];
#pragma unroll
        for (int off = 32; off >= 1; off >>= 1) s += __shfl_xor(s, off, 64);
        float mn = fmaxf(m, s);
        float scale = __expf(m - mn);   // 0 on first iter (m=-inf)
        float p = __expf(s - mn);
        l = l * scale + p;
        unpack8(ev, ef);
#pragma unroll
        for (int j = 0; j < 8; j++) acc[j] = acc[j] * scale + p * ef[j];
        m = mn;
    }

    // block combine: 4 waves -> one chunk partial
    __shared__ float sm[4], sl[4];
    __shared__ float sacc[4][512];
    if (lane == 0) { sm[wave] = m; sl[wave] = l; }
    __syncthreads();
    float bm = fmaxf(fmaxf(sm[0], sm[1]), fmaxf(sm[2], sm[3]));
    float f = __expf(m - bm);
#pragma unroll
    for (int j = 0; j < 8; j++) sacc[wave][lane * 8 + j] = acc[j] * f;
    __syncthreads();
    float s0 = sacc[0][tid] + sacc[1][tid] + sacc[2][tid] + sacc[3][tid];
    float s1 = sacc[0][tid + 256] + sacc[1][tid + 256] + sacc[2][tid + 256] + sacc[3][tid + 256];
    size_t po = ((size_t)(b * NCH + ch)) * 512;
    pacc[po + tid] = s0;
    pacc[po + tid + 256] = s1;
    if (tid == 0) {
        pm[b * NCH + ch] = bm;
        pl[b * NCH + ch] = sl[0] * __expf(sm[0] - bm) + sl[1] * __expf(sm[1] - bm) +
                           sl[2] * __expf(sm[2] - bm) + sl[3] * __expf(sm[3] - bm);
    }
}

// ---------------- combine chunk partials -> Xa[b,d] ----------------
__global__ void combine_kernel(const float* __restrict__ pm, const float* __restrict__ pl,
                               const float* __restrict__ pacc, float* __restrict__ Xa) {
    int b = blockIdx.x, tid = threadIdx.x;
    __shared__ float w[NCH];
    float mg = -1e30f;
#pragma unroll
    for (int i = 0; i < NCH; i++) mg = fmaxf(mg, pm[b * NCH + i]);
    float L = 0.f;
#pragma unroll
    for (int i = 0; i < NCH; i++) L += pl[b * NCH + i] * __expf(pm[b * NCH + i] - mg);
    if (tid < NCH) w[tid] = __expf(pm[b * NCH + tid] - mg);
    __syncthreads();
    float inv = __builtin_amdgcn_rcpf(L);
    for (int d = tid; d < 512; d += 256) {
        float s = 0.f;
#pragma unroll
        for (int i = 0; i < NCH; i++) s += w[i] * pacc[((size_t)(b * NCH + i)) * 512 + d];
        Xa[b * 512 + d] = s * inv;
    }
}

// ------- h_in = concat(x_t, Xa) @ W3 + b3, weights read once per step -------
// grid 32 (u-chunks of 16); block 256: tx=u (16), ty=b-slot (16) -> b=ty, ty+16
__global__ void mix_kernel(const float* __restrict__ dec, const float* __restrict__ Xa,
                           const float* __restrict__ W3, const float* __restrict__ b3,
                           float* __restrict__ h_in, int t) {
    int u0 = blockIdx.x * 16;
    int tx = threadIdx.x & 15, ty = threadIdx.x >> 4;
    __shared__ float s[32][65];
    __shared__ float Ws[64][17];
    float acc0 = 0.f, acc1 = 0.f;
    for (int k0 = 0; k0 < 1024; k0 += 64) {
#pragma unroll
        for (int i = 0; i < 8; i++) {
            int idx = threadIdx.x + 256 * i;
            int bb = idx >> 6, kk = idx & 63;
            int k = k0 + kk;
            s[bb][kk] = (k < 512) ? dec[((size_t)bb * TDEC + t) * 512 + k]
                                  : Xa[bb * 512 + (k - 512)];
        }
#pragma unroll
        for (int i = 0; i < 4; i++) {
            int idx = threadIdx.x + 256 * i;
            int kk = idx >> 4, uu = idx & 15;
            Ws[kk][uu] = W3[(size_t)(k0 + kk) * 512 + u0 + uu];
        }
        __syncthreads();
#pragma unroll
        for (int k = 0; k < 64; k++) {
            float w = Ws[k][tx];
            acc0 += s[ty][k] * w;
            acc1 += s[ty + 16][k] * w;
        }
        __syncthreads();
    }
    float bv = b3[u0 + tx];
    h_in[ty * 512 + u0 + tx] = acc0 + bv;
    h_in[(ty + 16) * 512 + u0 + tx] = acc1 + bv;
}

// ---------------- z = h_in @ Wk + h @ Wr + bias : [32, 2048] ----------------
__global__ void z_kernel(const float* __restrict__ h_in, const float* __restrict__ h,
                         const float* __restrict__ Wk, const float* __restrict__ Wr,
                         const float* __restrict__ bias, float* __restrict__ z) {
    int gc = blockIdx.x * 16;
    int tx = threadIdx.x & 15, ty = threadIdx.x >> 4;
    __shared__ float his[32][65], hcs[32][65], Ks[64][16], Rs[64][16];
    float acc0 = 0.f, acc1 = 0.f;
    for (int u0 = 0; u0 < 512; u0 += 64) {
#pragma unroll
        for (int i = 0; i < 8; i++) {
            int idx = threadIdx.x + 256 * i;
            int bb = idx >> 6, uu = idx & 63;
            his[bb][uu] = h_in[bb * 512 + u0 + uu];
            hcs[bb][uu] = h[bb * 512 + u0 + uu];
        }
#pragma unroll
        for (int i = 0; i < 4; i++) {
            int idx = threadIdx.x + 256 * i;
            int uu = idx >> 4, gg = idx & 15;
            Ks[uu][gg] = Wk[(size_t)(u0 + uu) * 2048 + gc + gg];
            Rs[uu][gg] = Wr[(size_t)(u0 + uu) * 2048 + gc + gg];
        }
        __syncthreads();
#pragma unroll
        for (int u = 0; u < 64; u++) {
            float kv = Ks[u][tx], rv = Rs[u][tx];
            acc0 += his[ty][u] * kv + hcs[ty][u] * rv;
            acc1 += his[ty + 16][u] * kv + hcs[ty + 16][u] * rv;
        }
        __syncthreads();
    }
    float bv = bias[gc + tx];
    z[(size_t)ty * 2048 + gc + tx] = acc0 + bv;
    z[(size_t)(ty + 16) * 2048 + gc + tx] = acc1 + bv;
}

// ---------------- gates + state update + output write ----------------
__global__ void gate_kernel(const float* __restrict__ z, float* __restrict__ c,
                            float* __restrict__ h, float* __restrict__ out, int t) {
    int idx = blockIdx.x * 256 + threadIdx.x;  // 0..16383
    int b = idx >> 9, u = idx & 511;
    const float* zb = z + (size_t)b * 2048;
    float zi = zb[u], zf = zb[512 + u], zg = zb[1024 + u], zo = zb[1536 + u];
    float ig = fast_sig(zi);
    float fg = fast_sig(zf);
    float gg = fast_tanh(zg);
    float og = fast_sig(zo);
    float cn = fg * c[idx] + ig * gg;
    float hn = og * fast_tanh(cn);
    c[idx] = cn;
    h[idx] = hn;
    out[((size_t)b * TDEC + t) * 512 + u] = hn;
}

extern "C" void kernel_launch(void* const* d_in, const int* in_sizes, int n_in,
                              void* d_out, int out_size, void* d_ws, size_t ws_size,
                              hipStream_t stream) {
    const float* enc = (const float*)d_in[0];
    const float* dec = (const float*)d_in[1];
    const float* W1 = (const float*)d_in[2];
    const float* W2 = (const float*)d_in[3];
    const float* b2 = (const float*)d_in[4];
    const float* V = (const float*)d_in[5];
    const float* W3 = (const float*)d_in[6];
    const float* b3 = (const float*)d_in[7];
    const float* Wk = (const float*)d_in[8];
    const float* Wr = (const float*)d_in[9];
    const float* bias = (const float*)d_in[10];
    float* out = (float*)d_out;

    char* ws = (char*)d_ws;
    size_t o = 0;
    ushort_t* xW1h = (ushort_t*)(ws + o); o += (size_t)B * TENC * 512 * 2;  // 67.1 MB
    ushort_t* ench = (ushort_t*)(ws + o); o += (size_t)B * TENC * 512 * 2;  // 67.1 MB
    float* pacc = (float*)(ws + o); o += (size_t)B * NCH * 512 * 4;         // 1 MB
    float* h = (float*)(ws + o);    o += B * 512 * 4;
    float* c = (float*)(ws + o);    o += B * 512 * 4;
    float* hW2 = (float*)(ws + o);  o += B * 512 * 4;
    float* Xa = (float*)(ws + o);   o += B * 512 * 4;
    float* h_in = (float*)(ws + o); o += B * 512 * 4;
    float* z = (float*)(ws + o);    o += B * 2048 * 4;
    float* pm = (float*)(ws + o);   o += B * NCH * 4;
    float* pl = (float*)(ws + o);   o += B * NCH * 4;

    // zero h and c (contiguous)
    hipMemsetAsync(h, 0, (size_t)2 * B * 512 * sizeof(float), stream);

    cvt_kernel<<<16384, 256, 0, stream>>>(enc, ench);
    gemm_xw1_kernel<<<dim3(8, 1024), 256, 0, stream>>>(enc, W1, xW1h);

    for (int t = 0; t < TDEC; t++) {
        hw2_kernel<<<dim3(32, 2), 256, 0, stream>>>(h, W2, b2, hW2);
        attn_kernel<<<dim3(32, NCH), 256, 0, stream>>>(xW1h, ench, hW2, V, pm, pl, pacc);
        combine_kernel<<<32, 256, 0, stream>>>(pm, pl, pacc, Xa);
        mix_kernel<<<32, 256, 0, stream>>>(dec, Xa, W3, b3, h_in, t);
        z_kernel<<<128, 256, 0, stream>>>(h_in, h, Wk, Wr, bias, z);
        gate_kernel<<<64, 256, 0, stream>>>(z, c, h, out, t);
    }
}